// Round 5
// baseline (554.370 us; speedup 1.0000x reference)
//
#include <hip/hip_runtime.h>

typedef short short8 __attribute__((ext_vector_type(8)));
typedef float f32x4 __attribute__((ext_vector_type(4)));
typedef int int4v __attribute__((ext_vector_type(4)));
typedef unsigned uint2v __attribute__((ext_vector_type(2)));
typedef unsigned short ushort;

#define MFMA(a, b, c) __builtin_amdgcn_mfma_f32_16x16x32_bf16(a, b, c, 0, 0, 0)

// Pin: force value live-in-register at this point (prevents load sinking).
// Scalar 32-bit operands only — vector asm operands are rejected by clang on gfx950.
// NOTE: macro parameter must not be named 'x'/'y'/'z'/'w' (member-access capture!).
#define PIN8(v8_) do { int4v _t; __builtin_memcpy(&_t, &(v8_), 16); \
    asm volatile("" :: "v"(_t[0]), "v"(_t[1]), "v"(_t[2]), "v"(_t[3])); } while (0)
#define PINF4(v4_) asm volatile("" :: "v"((v4_).x), "v"((v4_).y), "v"((v4_).z), "v"((v4_).w))

// ---- ws layout (ushort element offsets) ---- (fragment-packed weights)
#define WS_WQT 0        // 18 frags (nt*3+kt) — also valid as Wq^T A-operand frags
#define WS_WKT 9216     // 36 frags (kt6*6+nt)
#define WS_WVT 27648    // 36 frags (kt6*6+nt)
#define WS_WOT 46080    // 18 frags (nt*3+kt)
#define WS_BIAS 55296   // bias table bf16 [225*6], PRE-SCALED by log2(e)
#define WS_TOTAL 56646

// ---- LDS layout (ushort offsets), total 39052 B ----
// A region roles: A_q -> A_kv0 -> A_kv1 -> K16'[tok][h*16+d] -> obuf[tok][h*16+d]
#define STR_A 104
#define U_A    0        // 64*104          = 6656 ushorts
#define U_VT   6656     // [6][16][72]     = 6912
#define STR_VT 72
#define U_PS   13568    // 4 waves * 1152 (P buffer, stride 72 x 16 rows)
#define U_BIAS 18176    // 1350
#define U_TOTAL 19526   // = 39052 bytes

#define LOG2E 1.44269504f

__device__ __forceinline__ ushort f2bf(float v) {
    unsigned u = __float_as_uint(v);
    u = (u + 0x7FFFu + ((u >> 16) & 1u)) >> 16;   // RNE
    return (ushort)u;
}
__device__ __forceinline__ unsigned cvtpk_bf16(float lo, float hi) {
    unsigned r;
    asm("v_cvt_pk_bf16_f32 %0, %1, %2" : "=v"(r) : "v"(lo), "v"(hi));
    return r;
}

__global__ void prep_weights(const float* __restrict__ Wq, const float* __restrict__ Wk,
                             const float* __restrict__ Wv, const float* __restrict__ Wo,
                             const float* __restrict__ btab, ushort* __restrict__ ws) {
    int idx = blockIdx.x * 256 + threadIdx.x;
    if (idx < WS_WKT) {                         // WqT packed, frag = nt*3+kt
        int f = idx >> 9, w = idx & 511, lane = w >> 3, j = w & 7;
        int nt = f / 3, kt = f % 3;
        int n = nt * 16 + (lane & 15), k = kt * 32 + (lane >> 4) * 8 + j;
        ws[idx] = f2bf(Wq[k * 96 + n]);
    } else if (idx < WS_WVT) {                  // WkT packed, frag = kt6*6+nt
        int t = idx - WS_WKT;
        int f = t >> 9, w = t & 511, lane = w >> 3, j = w & 7;
        int kt6 = f / 6, nt = f % 6;
        int n = nt * 16 + (lane & 15), k = kt6 * 32 + (lane >> 4) * 8 + j;
        ws[idx] = f2bf(Wk[k * 96 + n]);
    } else if (idx < WS_WOT) {                  // WvT packed, frag = kt6*6+nt
        int t = idx - WS_WVT;
        int f = t >> 9, w = t & 511, lane = w >> 3, j = w & 7;
        int kt6 = f / 6, nt = f % 6;
        int n = nt * 16 + (lane & 15), k = kt6 * 32 + (lane >> 4) * 8 + j;
        ws[idx] = f2bf(Wv[k * 96 + n]);
    } else if (idx < WS_BIAS) {                 // WoT packed, frag = nt*3+kt
        int t = idx - WS_WOT;
        int f = t >> 9, w = t & 511, lane = w >> 3, j = w & 7;
        int nt = f / 3, kt = f % 3;
        int n = nt * 16 + (lane & 15), k = kt * 32 + (lane >> 4) * 8 + j;
        ws[idx] = f2bf(Wo[k * 96 + n]);
    } else if (idx < WS_TOTAL) {                // bias table -> bf16, pre-scaled for exp2 softmax
        ws[idx] = f2bf(btab[idx - WS_BIAS] * LOG2E);
    }
}

__global__ __launch_bounds__(256, 3) void swin_attn(
    const float* __restrict__ xq, const float* __restrict__ xkv,
    const float* __restrict__ bq, const float* __restrict__ bk,
    const float* __restrict__ bv, const float* __restrict__ bo,
    const ushort* __restrict__ ws, float* __restrict__ out)
{
    __shared__ __align__(16) ushort smem[U_TOTAL + 8];
    const int tid = threadIdx.x;
    const int wave = tid >> 6, lane = tid & 63;
    const int l15 = lane & 15, quad = lane >> 4;
    int wid = ((blockIdx.x & 7) << 9) | (blockIdx.x >> 3);   // XCD swizzle
    const int b = wid >> 10;
    const int wh = (wid >> 5) & 31, ww = wid & 31;
    const int h0 = wh * 8, w0 = ww * 8;
    const int mt = wave;

    ushort* A     = smem + U_A;
    ushort* vt    = smem + U_VT;
    ushort* ps    = smem + U_PS + wave * 1152;   // wave-private P (stride 72, 16 rows)
    ushort* biasl = smem + U_BIAS;

    // K/V projection bias per-lane (C-seed columns, n = d = l15)
    float bkr[6], bvr[6];
    #pragma unroll
    for (int h = 0; h < 6; ++h) { bkr[h] = bk[h * 16 + l15]; bvr[h] = bv[h * 16 + l15]; }

    int pc[3], pi[3];
    #pragma unroll
    for (int t = 0; t < 3; ++t) { int p = tid + t * 256; pc[t] = p % 96; pi[t] = p / 96; }

    // ---- phase 0: issue xq loads, stage bias table, write A_q ----
    const float* xqb = xq + (size_t)b * 96 * 65536;
    float4 pf[3][2];
    #pragma unroll
    for (int t = 0; t < 3; ++t) {
        const float* g = xqb + (size_t)pc[t] * 65536 + (h0 + pi[t]) * 256 + w0;
        pf[t][0] = *(const float4*)g; pf[t][1] = *(const float4*)(g + 4);
    }
    for (int i = tid; i < 1350; i += 256) biasl[i] = ws[WS_BIAS + i];

    #pragma unroll
    for (int t = 0; t < 3; ++t) {
        int base = (pi[t] * 8) * STR_A + pc[t];
        A[base]             = f2bf(pf[t][0].x); A[base + STR_A]     = f2bf(pf[t][0].y);
        A[base + 2 * STR_A] = f2bf(pf[t][0].z); A[base + 3 * STR_A] = f2bf(pf[t][0].w);
        A[base + 4 * STR_A] = f2bf(pf[t][1].x); A[base + 5 * STR_A] = f2bf(pf[t][1].y);
        A[base + 6 * STR_A] = f2bf(pf[t][1].z); A[base + 7 * STR_A] = f2bf(pf[t][1].w);
    }
    __syncthreads();   // B1: A_q visible

    // ---- phase 1: issue kv0 loads (pinned); TRANSPOSED q-projection (all heads) ----
    const float* xkvb = xkv + (size_t)b * 192 * 65536;
    float4 pg[3][2];
    #pragma unroll
    for (int t = 0; t < 3; ++t) {
        const float* g = xkvb + (size_t)pc[t] * 65536 + (h0 + pi[t]) * 256 + w0;
        pg[t][0] = *(const float4*)g; pg[t][1] = *(const float4*)(g + 4);
        PINF4(pg[t][0]); PINF4(pg[t][1]);
    }
    float4 bqv[6];
    #pragma unroll
    for (int h = 0; h < 6; ++h) { bqv[h] = *(const float4*)(bq + h * 16 + quad * 4); PINF4(bqv[h]); }

    const int arow = (mt * 16 + l15) * STR_A + quad * 8;
    short8 a0 = *(const short8*)(A + arow);
    short8 a1 = *(const short8*)(A + arow + 32);
    short8 a2 = *(const short8*)(A + arow + 64);
    // Q^T = MFMA(Wq^T-frag as A, x-frag as B): lane holds q[tok=l15][d = quad*4+r]
    unsigned qpk[12];
    {
        short8 wq0 = *(const short8*)(ws + WS_WQT + (0 * 64 + lane) * 8);
        short8 wq1 = *(const short8*)(ws + WS_WQT + (1 * 64 + lane) * 8);
        short8 wq2 = *(const short8*)(ws + WS_WQT + (2 * 64 + lane) * 8);
        PIN8(wq0); PIN8(wq1); PIN8(wq2);
        #pragma unroll
        for (int h = 0; h < 6; ++h) {
            short8 c0 = wq0, c1 = wq1, c2 = wq2;
            if (h < 5) {
                wq0 = *(const short8*)(ws + WS_WQT + (((h + 1) * 3 + 0) * 64 + lane) * 8);
                wq1 = *(const short8*)(ws + WS_WQT + (((h + 1) * 3 + 1) * 64 + lane) * 8);
                wq2 = *(const short8*)(ws + WS_WQT + (((h + 1) * 3 + 2) * 64 + lane) * 8);
                PIN8(wq0); PIN8(wq1); PIN8(wq2);
            }
            f32x4 qa = {bqv[h].x, bqv[h].y, bqv[h].z, bqv[h].w};
            qa = MFMA(c0, a0, qa);
            qa = MFMA(c1, a1, qa);
            qa = MFMA(c2, a2, qa);
            const float qs = 0.25f * LOG2E;
            qpk[h * 2]     = cvtpk_bf16(qa[0] * qs, qa[1] * qs);
            qpk[h * 2 + 1] = cvtpk_bf16(qa[2] * qs, qa[3] * qs);
        }
    }
    __syncthreads();   // B2: all A_q reads done

    // ---- phase 2: stage kv0; preload kt=0 weight frags (pinned) across barrier ----
    #pragma unroll
    for (int t = 0; t < 3; ++t) {
        int base = (pi[t] * 8) * STR_A + pc[t];
        A[base]             = f2bf(pg[t][0].x); A[base + STR_A]     = f2bf(pg[t][0].y);
        A[base + 2 * STR_A] = f2bf(pg[t][0].z); A[base + 3 * STR_A] = f2bf(pg[t][0].w);
        A[base + 4 * STR_A] = f2bf(pg[t][1].x); A[base + 5 * STR_A] = f2bf(pg[t][1].y);
        A[base + 6 * STR_A] = f2bf(pg[t][1].z); A[base + 7 * STR_A] = f2bf(pg[t][1].w);
    }
    f32x4 accK[6], accV[6];
    #pragma unroll
    for (int n = 0; n < 6; ++n) {
        accK[n] = {bkr[n], bkr[n], bkr[n], bkr[n]};
        accV[n] = {bvr[n], bvr[n], bvr[n], bvr[n]};
    }
    short8 wk[6], wv[6];
    #pragma unroll
    for (int nt = 0; nt < 6; ++nt) {
        wk[nt] = *(const short8*)(ws + WS_WKT + (nt * 64 + lane) * 8); PIN8(wk[nt]);
    }
    #pragma unroll
    for (int nt = 0; nt < 6; ++nt) {
        wv[nt] = *(const short8*)(ws + WS_WVT + (nt * 64 + lane) * 8); PIN8(wv[nt]);
    }
    __syncthreads();   // B3: A_kv0 visible

    // kv0 cluster, software-pipelined weight loads
    #pragma unroll
    for (int kt = 0; kt < 3; ++kt) {
        short8 a = *(const short8*)(A + arow + kt * 32);
        #pragma unroll
        for (int nt = 0; nt < 6; ++nt) accK[nt] = MFMA(a, wk[nt], accK[nt]);
        if (kt < 2) {
            #pragma unroll
            for (int nt = 0; nt < 6; ++nt) {
                wk[nt] = *(const short8*)(ws + WS_WKT + ((((kt + 1) * 6) + nt) * 64 + lane) * 8);
                PIN8(wk[nt]);
            }
        }
        #pragma unroll
        for (int nt = 0; nt < 6; ++nt) accV[nt] = MFMA(a, wv[nt], accV[nt]);
        if (kt < 2) {
            #pragma unroll
            for (int nt = 0; nt < 6; ++nt) {
                wv[nt] = *(const short8*)(ws + WS_WVT + ((((kt + 1) * 6) + nt) * 64 + lane) * 8);
                PIN8(wv[nt]);
            }
        }
    }
    // issue kv1 x loads (pinned so they can't sink past B4)
    #pragma unroll
    for (int t = 0; t < 3; ++t) {
        const float* g = xkvb + (size_t)(96 + pc[t]) * 65536 + (h0 + pi[t]) * 256 + w0;
        pf[t][0] = *(const float4*)g; pf[t][1] = *(const float4*)(g + 4);
        PINF4(pf[t][0]); PINF4(pf[t][1]);
    }
    __syncthreads();   // B4: all A_kv0 reads done

    #pragma unroll
    for (int t = 0; t < 3; ++t) {
        int base = (pi[t] * 8) * STR_A + pc[t];
        A[base]             = f2bf(pf[t][0].x); A[base + STR_A]     = f2bf(pf[t][0].y);
        A[base + 2 * STR_A] = f2bf(pf[t][0].z); A[base + 3 * STR_A] = f2bf(pf[t][0].w);
        A[base + 4 * STR_A] = f2bf(pf[t][1].x); A[base + 5 * STR_A] = f2bf(pf[t][1].y);
        A[base + 6 * STR_A] = f2bf(pf[t][1].z); A[base + 7 * STR_A] = f2bf(pf[t][1].w);
    }
    // preload second-half kt=3 frags across the barrier
    #pragma unroll
    for (int nt = 0; nt < 6; ++nt) {
        wk[nt] = *(const short8*)(ws + WS_WKT + (((3 * 6) + nt) * 64 + lane) * 8); PIN8(wk[nt]);
    }
    #pragma unroll
    for (int nt = 0; nt < 6; ++nt) {
        wv[nt] = *(const short8*)(ws + WS_WVT + (((3 * 6) + nt) * 64 + lane) * 8); PIN8(wv[nt]);
    }
    __syncthreads();   // B5: A_kv1 visible

    #pragma unroll
    for (int kt = 0; kt < 3; ++kt) {
        short8 a = *(const short8*)(A + arow + kt * 32);
        #pragma unroll
        for (int nt = 0; nt < 6; ++nt) accK[nt] = MFMA(a, wk[nt], accK[nt]);
        if (kt < 2) {
            #pragma unroll
            for (int nt = 0; nt < 6; ++nt) {
                wk[nt] = *(const short8*)(ws + WS_WKT + ((((4 + kt) * 6) + nt) * 64 + lane) * 8);
                PIN8(wk[nt]);
            }
        }
        #pragma unroll
        for (int nt = 0; nt < 6; ++nt) accV[nt] = MFMA(a, wv[nt], accV[nt]);
        if (kt < 2) {
            #pragma unroll
            for (int nt = 0; nt < 6; ++nt) {
                wv[nt] = *(const short8*)(ws + WS_WVT + ((((4 + kt) * 6) + nt) * 64 + lane) * 8);
                PIN8(wv[nt]);
            }
        }
    }
    // K16' into A region (own rows) + VT (token-contig per head)
    #pragma unroll
    for (int nt = 0; nt < 6; ++nt) {
        ushort* dk = A + (mt * 16 + quad * 4) * STR_A + nt * 16 + l15;
        ushort* dv = vt + nt * (16 * STR_VT) + l15 * STR_VT + (mt * 16 + quad * 4);
        #pragma unroll
        for (int r = 0; r < 4; ++r) {
            dk[r * STR_A] = f2bf(accK[nt][r]);
            dv[r]         = f2bf(accV[nt][r]);
        }
    }
    __syncthreads();   // B6: K16' + VT visible

    // ---- rel-bias byte offsets: q = mt*16+l15 (fixed), k = nt*16 + quad*4 + r ----
    const int qt = mt * 16 + l15;
    const int i1 = qt >> 3, j1 = qt & 7;
    int boff[4][4];
    #pragma unroll
    for (int nt = 0; nt < 4; ++nt)
        #pragma unroll
        for (int r = 0; r < 4; ++r) {
            int k2 = nt * 16 + quad * 4 + r, i2 = k2 >> 3, j2 = k2 & 7;
            boff[nt][r] = ((i1 - i2 + 7) * 15 + (j1 - j2 + 7)) * 6;
        }

    const int bp0 = (l15 + (quad << 5)) << 2;   // bpermute byte indices
    const int bp1 = bp0 + (16 << 2);
    const int psrow = l15 * 72;                  // P row base (ushort), q = l15

    // ---- head loop, 2-head batches, S^T attention ----
    f32x4 accO[6];
    short8 zero8 = {};
    #pragma unroll
    for (int hp = 0; hp < 3; ++hp) {
        const int hA = hp * 2, hB = hA + 1;
        // aq via bpermute: lane gets q[tok=l15][d = quad*8+j] (garbage for quad>=2, harmless:
        // A-operand is zeroed there, and values are finite bf16)
        int A0 = __builtin_amdgcn_ds_bpermute(bp0, (int)qpk[hA * 2]);
        int A1 = __builtin_amdgcn_ds_bpermute(bp0, (int)qpk[hA * 2 + 1]);
        int A2 = __builtin_amdgcn_ds_bpermute(bp1, (int)qpk[hA * 2]);
        int A3 = __builtin_amdgcn_ds_bpermute(bp1, (int)qpk[hA * 2 + 1]);
        int B0 = __builtin_amdgcn_ds_bpermute(bp0, (int)qpk[hB * 2]);
        int B1 = __builtin_amdgcn_ds_bpermute(bp0, (int)qpk[hB * 2 + 1]);
        int B2 = __builtin_amdgcn_ds_bpermute(bp1, (int)qpk[hB * 2]);
        int B3 = __builtin_amdgcn_ds_bpermute(bp1, (int)qpk[hB * 2 + 1]);
        union { int4v i; short8 s; } ua, ub;
        ua.i = (int4v){A0, A1, A2, A3};
        ub.i = (int4v){B0, B1, B2, B3};
        short8 aqA = ua.s, aqB = ub.s;

        short8 kfA[4], kfB[4];
        #pragma unroll
        for (int nt = 0; nt < 4; ++nt) { kfA[nt] = zero8; kfB[nt] = zero8; }
        if (quad < 2) {
            #pragma unroll
            for (int nt = 0; nt < 4; ++nt) {
                kfA[nt] = *(const short8*)(A + (nt * 16 + l15) * STR_A + hA * 16 + quad * 8);
                kfB[nt] = *(const short8*)(A + (nt * 16 + l15) * STR_A + hB * 16 + quad * 8);
            }
        }
        // paired bias reads: one b32 covers heads hA (lo) and hB (hi); 4-byte aligned
        unsigned bb[4][4];
        #pragma unroll
        for (int nt = 0; nt < 4; ++nt)
            #pragma unroll
            for (int r = 0; r < 4; ++r)
                bb[nt][r] = *(const unsigned*)(biasl + boff[nt][r] + hA);

        f32x4 sA[4], sB[4];
        #pragma unroll
        for (int nt = 0; nt < 4; ++nt) {
            f32x4 c;
            c[0] = __uint_as_float(bb[nt][0] << 16); c[1] = __uint_as_float(bb[nt][1] << 16);
            c[2] = __uint_as_float(bb[nt][2] << 16); c[3] = __uint_as_float(bb[nt][3] << 16);
            sA[nt] = MFMA(kfA[nt], aqA, c);
        }
        #pragma unroll
        for (int nt = 0; nt < 4; ++nt) {
            f32x4 c;
            c[0] = __uint_as_float(bb[nt][0] & 0xFFFF0000u); c[1] = __uint_as_float(bb[nt][1] & 0xFFFF0000u);
            c[2] = __uint_as_float(bb[nt][2] & 0xFFFF0000u); c[3] = __uint_as_float(bb[nt][3] & 0xFFFF0000u);
            sB[nt] = MFMA(kfB[nt], aqB, c);
        }
        // softmax: rows q=l15 live in lanes {l15, +16, +32, +48}; in-lane 16 + 2 shuffles
        float mA, mB, lA, lB;
        {
            float a_ = fmaxf(fmaxf(sA[0][0], sA[0][1]), fmaxf(sA[0][2], sA[0][3]));
            float b_ = fmaxf(fmaxf(sA[1][0], sA[1][1]), fmaxf(sA[1][2], sA[1][3]));
            float c_ = fmaxf(fmaxf(sA[2][0], sA[2][1]), fmaxf(sA[2][2], sA[2][3]));
            float d_ = fmaxf(fmaxf(sA[3][0], sA[3][1]), fmaxf(sA[3][2], sA[3][3]));
            mA = fmaxf(fmaxf(a_, b_), fmaxf(c_, d_));
            float a2_ = fmaxf(fmaxf(sB[0][0], sB[0][1]), fmaxf(sB[0][2], sB[0][3]));
            float b2_ = fmaxf(fmaxf(sB[1][0], sB[1][1]), fmaxf(sB[1][2], sB[1][3]));
            float c2_ = fmaxf(fmaxf(sB[2][0], sB[2][1]), fmaxf(sB[2][2], sB[2][3]));
            float d2_ = fmaxf(fmaxf(sB[3][0], sB[3][1]), fmaxf(sB[3][2], sB[3][3]));
            mB = fmaxf(fmaxf(a2_, b2_), fmaxf(c2_, d2_));
        }
        mA = fmaxf(mA, __shfl_xor(mA, 16)); mA = fmaxf(mA, __shfl_xor(mA, 32));
        mB = fmaxf(mB, __shfl_xor(mB, 16)); mB = fmaxf(mB, __shfl_xor(mB, 32));
        #pragma unroll
        for (int nt = 0; nt < 4; ++nt)
            #pragma unroll
            for (int r = 0; r < 4; ++r) {
                sA[nt][r] = exp2f(sA[nt][r] - mA);
                sB[nt][r] = exp2f(sB[nt][r] - mB);
            }
        {
            float a_ = (sA[0][0] + sA[0][1]) + (sA[0][2] + sA[0][3]);
            float b_ = (sA[1][0] + sA[1][1]) + (sA[1][2] + sA[1][3]);
            float c_ = (sA[2][0] + sA[2][1]) + (sA[2][2] + sA[2][3]);
            float d_ = (sA[3][0] + sA[3][1]) + (sA[3][2] + sA[3][3]);
            lA = (a_ + b_) + (c_ + d_);
            float a2_ = (sB[0][0] + sB[0][1]) + (sB[0][2] + sB[0][3]);
            float b2_ = (sB[1][0] + sB[1][1]) + (sB[1][2] + sB[1][3]);
            float c2_ = (sB[2][0] + sB[2][1]) + (sB[2][2] + sB[2][3]);
            float d2_ = (sB[3][0] + sB[3][1]) + (sB[3][2] + sB[3][3]);
            lB = (a2_ + b2_) + (c2_ + d2_);
        }
        lA += __shfl_xor(lA, 16); lA += __shfl_xor(lA, 32);
        lB += __shfl_xor(lB, 16); lB += __shfl_xor(lB, 32);
        float invA = __builtin_amdgcn_rcpf(lA);
        float invB = __builtin_amdgcn_rcpf(lB);

        // P-A write (b64, lane-contiguous k) + PV-A
        #pragma unroll
        for (int nt = 0; nt < 4; ++nt) {
            unsigned p0 = cvtpk_bf16(sA[nt][0] * invA, sA[nt][1] * invA);
            unsigned p1 = cvtpk_bf16(sA[nt][2] * invA, sA[nt][3] * invA);
            *(uint2v*)(ps + psrow + nt * 16 + quad * 4) = (uint2v){p0, p1};
        }
        f32x4 oA = {};
        #pragma unroll
        for (int k2 = 0; k2 < 2; ++k2) {
            short8 ap  = *(const short8*)(ps + psrow + k2 * 32 + quad * 8);
            short8 bv8 = *(const short8*)(vt + hA * (16 * STR_VT) + l15 * STR_VT + k2 * 32 + quad * 8);
            oA = MFMA(ap, bv8, oA);
        }
        // P-B write (same addresses; same-wave LDS order) + PV-B
        #pragma unroll
        for (int nt = 0; nt < 4; ++nt) {
            unsigned p0 = cvtpk_bf16(sB[nt][0] * invB, sB[nt][1] * invB);
            unsigned p1 = cvtpk_bf16(sB[nt][2] * invB, sB[nt][3] * invB);
            *(uint2v*)(ps + psrow + nt * 16 + quad * 4) = (uint2v){p0, p1};
        }
        f32x4 oB = {};
        #pragma unroll
        for (int k2 = 0; k2 < 2; ++k2) {
            short8 ap  = *(const short8*)(ps + psrow + k2 * 32 + quad * 8);
            short8 bv8 = *(const short8*)(vt + hB * (16 * STR_VT) + l15 * STR_VT + k2 * 32 + quad * 8);
            oB = MFMA(ap, bv8, oB);
        }
        accO[hA] = oA; accO[hB] = oB;
    }
    __syncthreads();   // B7: all K16' reads done before A-region reuse as obuf

    // ---- concat heads into obuf (own-wave rows) + out projection + store ----
    float bor_[6];
    #pragma unroll
    for (int h = 0; h < 6; ++h) bor_[h] = bo[h * 16 + l15];
    ushort* obuf = A;
    #pragma unroll
    for (int h = 0; h < 6; ++h)
        #pragma unroll
        for (int r = 0; r < 4; ++r)
            obuf[(mt * 16 + quad * 4 + r) * STR_A + h * 16 + l15] = f2bf(accO[h][r]);

    {
        int t0 = mt * 16 + quad * 4;
        int i = t0 >> 3, j0 = t0 & 7;
        short8 oa0 = *(const short8*)(obuf + arow);
        short8 oa1 = *(const short8*)(obuf + arow + 32);
        short8 oa2 = *(const short8*)(obuf + arow + 64);
        short8 wo0 = *(const short8*)(ws + WS_WOT + (0 * 64 + lane) * 8);
        short8 wo1 = *(const short8*)(ws + WS_WOT + (1 * 64 + lane) * 8);
        short8 wo2 = *(const short8*)(ws + WS_WOT + (2 * 64 + lane) * 8);
        PIN8(wo0); PIN8(wo1); PIN8(wo2);
        #pragma unroll
        for (int nt = 0; nt < 6; ++nt) {
            short8 c0 = wo0, c1 = wo1, c2 = wo2;
            if (nt < 5) {
                wo0 = *(const short8*)(ws + WS_WOT + (((nt + 1) * 3 + 0) * 64 + lane) * 8);
                wo1 = *(const short8*)(ws + WS_WOT + (((nt + 1) * 3 + 1) * 64 + lane) * 8);
                wo2 = *(const short8*)(ws + WS_WOT + (((nt + 1) * 3 + 2) * 64 + lane) * 8);
                PIN8(wo0); PIN8(wo1); PIN8(wo2);
            }
            f32x4 acc = {bor_[nt], bor_[nt], bor_[nt], bor_[nt]};
            acc = MFMA(oa0, c0, acc);
            acc = MFMA(oa1, c1, acc);
            acc = MFMA(oa2, c2, acc);
            int cout = nt * 16 + l15;
            float4 v4 = make_float4(acc[0], acc[1], acc[2], acc[3]);
            float* dst = out + (size_t)(b * 96 + cout) * 65536 + (h0 + i) * 256 + w0 + j0;
            *(float4*)dst = v4;
        }
    }
}

extern "C" void kernel_launch(void* const* d_in, const int* in_sizes, int n_in,
                              void* d_out, int out_size, void* d_ws, size_t ws_size,
                              hipStream_t stream) {
    const float* xq   = (const float*)d_in[0];
    const float* xkv  = (const float*)d_in[1];
    const float* Wq   = (const float*)d_in[2];
    const float* bq   = (const float*)d_in[3];
    const float* Wk   = (const float*)d_in[4];
    const float* bk   = (const float*)d_in[5];
    const float* Wv   = (const float*)d_in[6];
    const float* bv   = (const float*)d_in[7];
    const float* btab = (const float*)d_in[8];
    const float* Wo   = (const float*)d_in[9];
    const float* bo   = (const float*)d_in[10];
    ushort* ws = (ushort*)d_ws;
    float* out = (float*)d_out;

    hipLaunchKernelGGL(prep_weights, dim3((WS_TOTAL + 255) / 256), dim3(256), 0, stream,
                       Wq, Wk, Wv, Wo, btab, ws);
    hipLaunchKernelGGL(swin_attn, dim3(4096), dim3(256), 0, stream,
                       xq, xkv, bq, bk, bv, bo, ws, out);
}

// Round 6
// 463.679 us; speedup vs baseline: 1.1956x; 1.1956x over previous
//
#include <hip/hip_runtime.h>

typedef short short8 __attribute__((ext_vector_type(8)));
typedef float f32x4 __attribute__((ext_vector_type(4)));
typedef unsigned uint4v __attribute__((ext_vector_type(4)));
typedef unsigned short ushort;

#define MFMA(a, b, c) __builtin_amdgcn_mfma_f32_16x16x32_bf16(a, b, c, 0, 0, 0)
// DPP cross-lane reduce within 16-lane row: VALU pipe, no LDS latency
#define DPP_F(v, ctrl) __int_as_float(__builtin_amdgcn_update_dpp(0, __float_as_int(v), ctrl, 0xF, 0xF, true))

// ---- ws layout (ushort element offsets) ---- (fragment-packed weights)
#define WS_WQT 0        // 18 frags (nt*3+kt)
#define WS_WKT 9216     // 36 frags (kt6*6+nt)
#define WS_WVT 27648    // 36 frags (kt6*6+nt)
#define WS_WOT 46080    // 18 frags (nt*3+kt)
#define WS_BIAS 55296   // bias table bf16 [225*6], PRE-SCALED by log2(e)
#define WS_TOTAL 56646

// ---- LDS layout (ushort offsets), total 39052 B -> 4 blocks/CU ----
// A region roles:  A_q -> A_kv1 -> K16'[tok][h*16+d] -> obuf[tok][h*16+d]
// VT region roles: kv0 stage [64][104] -> VT'[6][16][72]
#define STR_A 104
#define U_A    0        // 6656 ushorts
#define U_VT   6656     // 6912 ushorts
#define STR_VT 72
#define U_PS   13568    // 4 waves * 1152 (P stride 72 x 16 rows; qscA@0/qscB@384 stride 24)
#define U_BIAS 18176    // 1350
#define U_TOTAL 19526   // = 39052 bytes

#define LOG2E 1.44269504f

__device__ __forceinline__ ushort f2bf(float v) {
    unsigned u = __float_as_uint(v);
    u = (u + 0x7FFFu + ((u >> 16) & 1u)) >> 16;   // RNE
    return (ushort)u;
}
__device__ __forceinline__ unsigned cvtpk_bf16(float lo, float hi) {
    unsigned r;
    asm("v_cvt_pk_bf16_f32 %0, %1, %2" : "=v"(r) : "v"(lo), "v"(hi));
    return r;
}

__global__ void prep_weights(const float* __restrict__ Wq, const float* __restrict__ Wk,
                             const float* __restrict__ Wv, const float* __restrict__ Wo,
                             const float* __restrict__ btab, ushort* __restrict__ ws) {
    int idx = blockIdx.x * 256 + threadIdx.x;
    if (idx < WS_WKT) {                         // WqT packed, frag = nt*3+kt
        int f = idx >> 9, w = idx & 511, lane = w >> 3, j = w & 7;
        int nt = f / 3, kt = f % 3;
        int n = nt * 16 + (lane & 15), k = kt * 32 + (lane >> 4) * 8 + j;
        ws[idx] = f2bf(Wq[k * 96 + n]);
    } else if (idx < WS_WVT) {                  // WkT packed, frag = kt6*6+nt
        int t = idx - WS_WKT;
        int f = t >> 9, w = t & 511, lane = w >> 3, j = w & 7;
        int kt6 = f / 6, nt = f % 6;
        int n = nt * 16 + (lane & 15), k = kt6 * 32 + (lane >> 4) * 8 + j;
        ws[idx] = f2bf(Wk[k * 96 + n]);
    } else if (idx < WS_WOT) {                  // WvT packed, frag = kt6*6+nt
        int t = idx - WS_WVT;
        int f = t >> 9, w = t & 511, lane = w >> 3, j = w & 7;
        int kt6 = f / 6, nt = f % 6;
        int n = nt * 16 + (lane & 15), k = kt6 * 32 + (lane >> 4) * 8 + j;
        ws[idx] = f2bf(Wv[k * 96 + n]);
    } else if (idx < WS_BIAS) {                 // WoT packed, frag = nt*3+kt
        int t = idx - WS_WOT;
        int f = t >> 9, w = t & 511, lane = w >> 3, j = w & 7;
        int nt = f / 3, kt = f % 3;
        int n = nt * 16 + (lane & 15), k = kt * 32 + (lane >> 4) * 8 + j;
        ws[idx] = f2bf(Wo[k * 96 + n]);
    } else if (idx < WS_TOTAL) {                // bias table -> bf16, pre-scaled for exp2 softmax
        ws[idx] = f2bf(btab[idx - WS_BIAS] * LOG2E);
    }
}

__global__ __launch_bounds__(256, 4) void swin_attn(
    const float* __restrict__ xq, const float* __restrict__ xkv,
    const float* __restrict__ bq, const float* __restrict__ bk,
    const float* __restrict__ bv, const float* __restrict__ bo,
    const ushort* __restrict__ ws, float* __restrict__ out)
{
    __shared__ __align__(16) ushort smem[U_TOTAL + 8];
    const int tid = threadIdx.x;
    const int wave = tid >> 6, lane = tid & 63;
    const int l15 = lane & 15, quad = lane >> 4;
    int wid = ((blockIdx.x & 7) << 9) | (blockIdx.x >> 3);   // XCD swizzle
    const int b = wid >> 10;
    const int wh = (wid >> 5) & 31, ww = wid & 31;
    const int h0 = wh * 8, w0 = ww * 8;
    const int mt = wave;

    ushort* A     = smem + U_A;
    ushort* vtreg = smem + U_VT;
    ushort* ps    = smem + U_PS + wave * 1152;
    ushort* biasl = smem + U_BIAS;

    // projection biases per-lane (C-seed col = out-ch = l15)
    float bqr[6], bkr[6], bvr[6];
    #pragma unroll
    for (int h = 0; h < 6; ++h) {
        bqr[h] = bq[h * 16 + l15]; bkr[h] = bk[h * 16 + l15]; bvr[h] = bv[h * 16 + l15];
    }

    // token-major staging: lane = token, wave = 24-channel group
    const int c0   = __builtin_amdgcn_readfirstlane(wave * 24);
    const int toff = (h0 + (lane >> 3)) * 256 + w0 + (lane & 7);   // float idx in plane
    const int wdst = lane * STR_A + c0;                             // ushort off in tile
    const int arow = (mt * 16 + l15) * STR_A + quad * 8;

    // ---- phase 0: issue xq loads; stage bias table; write A_q ----
    const float* xqb = xq + (size_t)b * 96 * 65536;
    float vq[24];
    #pragma unroll
    for (int j = 0; j < 24; ++j) vq[j] = xqb[(size_t)(c0 + j) * 65536 + toff];
    for (int i = tid; i < 1350; i += 256) biasl[i] = ws[WS_BIAS + i];
    {
        unsigned u[12];
        #pragma unroll
        for (int j = 0; j < 12; ++j) u[j] = cvtpk_bf16(vq[2 * j], vq[2 * j + 1]);
        uint4v* d = (uint4v*)(A + wdst);
        d[0] = (uint4v){u[0], u[1], u[2], u[3]};
        d[1] = (uint4v){u[4], u[5], u[6], u[7]};
        d[2] = (uint4v){u[8], u[9], u[10], u[11]};
    }
    __syncthreads();   // B1: A_q visible

    // ---- phase B: issue kv0 loads; q-proj (reads A); stage kv0 -> VT region ----
    const float* xkvb = xkv + (size_t)b * 192 * 65536;
    float vk0[24];
    #pragma unroll
    for (int j = 0; j < 24; ++j) vk0[j] = xkvb[(size_t)(c0 + j) * 65536 + toff];

    short8 a0 = *(const short8*)(A + arow);
    short8 a1 = *(const short8*)(A + arow + 32);
    short8 a2 = *(const short8*)(A + arow + 64);
    unsigned qpk[12];   // q (biased, scaled by 2^-2*log2e), packed bf16 pairs
    {
        short8 wq0 = *(const short8*)(ws + WS_WQT + (0 * 64 + lane) * 8);
        short8 wq1 = *(const short8*)(ws + WS_WQT + (1 * 64 + lane) * 8);
        short8 wq2 = *(const short8*)(ws + WS_WQT + (2 * 64 + lane) * 8);
        #pragma unroll
        for (int h = 0; h < 6; ++h) {
            short8 c0f = wq0, c1f = wq1, c2f = wq2;
            if (h < 5) {
                wq0 = *(const short8*)(ws + WS_WQT + (((h + 1) * 3 + 0) * 64 + lane) * 8);
                wq1 = *(const short8*)(ws + WS_WQT + (((h + 1) * 3 + 1) * 64 + lane) * 8);
                wq2 = *(const short8*)(ws + WS_WQT + (((h + 1) * 3 + 2) * 64 + lane) * 8);
            }
            f32x4 qa = {bqr[h], bqr[h], bqr[h], bqr[h]};
            qa = MFMA(a0, c0f, qa);
            qa = MFMA(a1, c1f, qa);
            qa = MFMA(a2, c2f, qa);
            const float qs = 0.25f * LOG2E;
            qpk[h * 2]     = cvtpk_bf16(qa[0] * qs, qa[1] * qs);
            qpk[h * 2 + 1] = cvtpk_bf16(qa[2] * qs, qa[3] * qs);
        }
    }
    {
        unsigned u[12];
        #pragma unroll
        for (int j = 0; j < 12; ++j) u[j] = cvtpk_bf16(vk0[2 * j], vk0[2 * j + 1]);
        uint4v* d = (uint4v*)(vtreg + wdst);
        d[0] = (uint4v){u[0], u[1], u[2], u[3]};
        d[1] = (uint4v){u[4], u[5], u[6], u[7]};
        d[2] = (uint4v){u[8], u[9], u[10], u[11]};
    }
    __syncthreads();   // B2: kv0 (VTreg) visible; all q-proj A-reads done

    // ---- phase C: kv0 MFMAs (VTreg); issue kv1 loads; stage kv1 -> A ----
    f32x4 accK[6], accV[6];
    #pragma unroll
    for (int n = 0; n < 6; ++n) {
        accK[n] = {bkr[n], bkr[n], bkr[n], bkr[n]};
        accV[n] = {bvr[n], bvr[n], bvr[n], bvr[n]};
    }
    #pragma unroll
    for (int kt = 0; kt < 3; ++kt) {
        short8 a = *(const short8*)(vtreg + arow + kt * 32);
        short8 wkf[6], wvf[6];
        #pragma unroll
        for (int nt = 0; nt < 6; ++nt)
            wkf[nt] = *(const short8*)(ws + WS_WKT + (((kt * 6) + nt) * 64 + lane) * 8);
        #pragma unroll
        for (int nt = 0; nt < 6; ++nt)
            wvf[nt] = *(const short8*)(ws + WS_WVT + (((kt * 6) + nt) * 64 + lane) * 8);
        #pragma unroll
        for (int nt = 0; nt < 6; ++nt) accK[nt] = MFMA(a, wkf[nt], accK[nt]);
        #pragma unroll
        for (int nt = 0; nt < 6; ++nt) accV[nt] = MFMA(a, wvf[nt], accV[nt]);
    }
    {
        float vk1[24];
        #pragma unroll
        for (int j = 0; j < 24; ++j) vk1[j] = xkvb[(size_t)(96 + c0 + j) * 65536 + toff];
        unsigned u[12];
        #pragma unroll
        for (int j = 0; j < 12; ++j) u[j] = cvtpk_bf16(vk1[2 * j], vk1[2 * j + 1]);
        uint4v* d = (uint4v*)(A + wdst);
        d[0] = (uint4v){u[0], u[1], u[2], u[3]};
        d[1] = (uint4v){u[4], u[5], u[6], u[7]};
        d[2] = (uint4v){u[8], u[9], u[10], u[11]};
    }
    __syncthreads();   // B3: kv1 (A) visible; all kv0 VTreg reads done

    // ---- phase D: kv1 MFMAs (A); K16' -> A own rows; VT' -> VTreg ----
    #pragma unroll
    for (int kt = 0; kt < 3; ++kt) {
        short8 a = *(const short8*)(A + arow + kt * 32);
        short8 wkf[6], wvf[6];
        #pragma unroll
        for (int nt = 0; nt < 6; ++nt)
            wkf[nt] = *(const short8*)(ws + WS_WKT + ((((3 + kt) * 6) + nt) * 64 + lane) * 8);
        #pragma unroll
        for (int nt = 0; nt < 6; ++nt)
            wvf[nt] = *(const short8*)(ws + WS_WVT + ((((3 + kt) * 6) + nt) * 64 + lane) * 8);
        #pragma unroll
        for (int nt = 0; nt < 6; ++nt) accK[nt] = MFMA(a, wkf[nt], accK[nt]);
        #pragma unroll
        for (int nt = 0; nt < 6; ++nt) accV[nt] = MFMA(a, wvf[nt], accV[nt]);
    }
    #pragma unroll
    for (int nt = 0; nt < 6; ++nt) {
        ushort* dk = A + (mt * 16 + quad * 4) * STR_A + nt * 16 + l15;
        ushort* dv = vtreg + nt * (16 * STR_VT) + l15 * STR_VT + (mt * 16 + quad * 4);
        #pragma unroll
        for (int r = 0; r < 4; ++r) {
            dk[r * STR_A] = f2bf(accK[nt][r]);
            dv[r]         = f2bf(accV[nt][r]);
        }
    }
    __syncthreads();   // B4: K16' + VT' visible

    // ---- rel-bias indices (head-independent), packed u16 pairs ----
    const int qtok0 = mt * 16 + quad * 4;
    unsigned bidxp[4][2];
    #pragma unroll
    for (int nt = 0; nt < 4; ++nt) {
        int kt2 = nt * 16 + l15, i2 = kt2 >> 3, j2 = kt2 & 7;
        unsigned v[4];
        #pragma unroll
        for (int r = 0; r < 4; ++r) {
            int qt = qtok0 + r, i1 = qt >> 3, j1 = qt & 7;
            v[r] = (unsigned)(((i1 - i2 + 7) * 15 + (j1 - j2 + 7)) * 6);
        }
        bidxp[nt][0] = v[0] | (v[1] << 16);
        bidxp[nt][1] = v[2] | (v[3] << 16);
    }

    // ---- head loop, 2-head batches; no-max softmax, deferred normalization ----
    f32x4 accO[6];
    short8 zero8 = {};
    #pragma unroll
    for (int hp = 0; hp < 3; ++hp) {
        const int hA = hp * 2, hB = hA + 1;
        asm volatile("" ::: "memory");   // keep DS program order across ps/qsc alias
        unsigned wloA = qpk[hA * 2], whiA = qpk[hA * 2 + 1];
        unsigned wloB = qpk[hB * 2], whiB = qpk[hB * 2 + 1];
        ps[(quad * 4 + 0) * 24 + l15] = (ushort)wloA;
        ps[(quad * 4 + 1) * 24 + l15] = (ushort)(wloA >> 16);
        ps[(quad * 4 + 2) * 24 + l15] = (ushort)whiA;
        ps[(quad * 4 + 3) * 24 + l15] = (ushort)(whiA >> 16);
        ps[384 + (quad * 4 + 0) * 24 + l15] = (ushort)wloB;
        ps[384 + (quad * 4 + 1) * 24 + l15] = (ushort)(wloB >> 16);
        ps[384 + (quad * 4 + 2) * 24 + l15] = (ushort)whiB;
        ps[384 + (quad * 4 + 3) * 24 + l15] = (ushort)(whiB >> 16);
        short8 aqA = zero8, aqB = zero8;
        short8 kfA[4] = {zero8, zero8, zero8, zero8};
        short8 kfB[4] = {zero8, zero8, zero8, zero8};
        if (quad < 2) {
            aqA = *(const short8*)(ps + l15 * 24 + quad * 8);
            aqB = *(const short8*)(ps + 384 + l15 * 24 + quad * 8);
            #pragma unroll
            for (int nt = 0; nt < 4; ++nt) {
                kfA[nt] = *(const short8*)(A + (nt * 16 + l15) * STR_A + hA * 16 + quad * 8);
                kfB[nt] = *(const short8*)(A + (nt * 16 + l15) * STR_A + hB * 16 + quad * 8);
            }
        }
        // paired bias reads: one b32 covers heads hA (lo) and hB (hi); always 4B-aligned
        unsigned bb[4][4];
        #pragma unroll
        for (int nt = 0; nt < 4; ++nt) {
            unsigned i01 = bidxp[nt][0], i23 = bidxp[nt][1];
            bb[nt][0] = *(const unsigned*)(biasl + (i01 & 0xFFFFu) + hA);
            bb[nt][1] = *(const unsigned*)(biasl + (i01 >> 16) + hA);
            bb[nt][2] = *(const unsigned*)(biasl + (i23 & 0xFFFFu) + hA);
            bb[nt][3] = *(const unsigned*)(biasl + (i23 >> 16) + hA);
        }
        f32x4 sA[4], sB[4];
        #pragma unroll
        for (int nt = 0; nt < 4; ++nt) {
            f32x4 c;
            c[0] = __uint_as_float(bb[nt][0] << 16); c[1] = __uint_as_float(bb[nt][1] << 16);
            c[2] = __uint_as_float(bb[nt][2] << 16); c[3] = __uint_as_float(bb[nt][3] << 16);
            sA[nt] = MFMA(aqA, kfA[nt], c);
        }
        #pragma unroll
        for (int nt = 0; nt < 4; ++nt) {
            f32x4 c;
            c[0] = __uint_as_float(bb[nt][0] & 0xFFFF0000u); c[1] = __uint_as_float(bb[nt][1] & 0xFFFF0000u);
            c[2] = __uint_as_float(bb[nt][2] & 0xFFFF0000u); c[3] = __uint_as_float(bb[nt][3] & 0xFFFF0000u);
            sB[nt] = MFMA(aqB, kfB[nt], c);
        }
        // softmax, no max-shift (|logit| << 1, exp2 safe; shift-invariant exact math)
        float prA[4][4], prB[4][4], invA4[4], invB4[4];
        #pragma unroll
        for (int r = 0; r < 4; ++r) {
            float lA = 0.f, lB = 0.f;
            #pragma unroll
            for (int nt = 0; nt < 4; ++nt) {
                prA[nt][r] = exp2f(sA[nt][r]); lA += prA[nt][r];
                prB[nt][r] = exp2f(sB[nt][r]); lB += prB[nt][r];
            }
            lA += DPP_F(lA, 0xB1);  lB += DPP_F(lB, 0xB1);    // quad_perm xor1
            lA += DPP_F(lA, 0x4E);  lB += DPP_F(lB, 0x4E);    // quad_perm xor2
            lA += DPP_F(lA, 0x124); lB += DPP_F(lB, 0x124);   // row_ror:4
            lA += DPP_F(lA, 0x128); lB += DPP_F(lB, 0x128);   // row_ror:8
            invA4[r] = __builtin_amdgcn_rcpf(lA);
            invB4[r] = __builtin_amdgcn_rcpf(lB);
        }
        // P-A write (UNNORMALIZED) + PV-A, then scale by inv (lane-uniform per quad-row)
        asm volatile("" ::: "memory");
        #pragma unroll
        for (int nt = 0; nt < 4; ++nt)
            #pragma unroll
            for (int r = 0; r < 4; ++r)
                ps[(quad * 4 + r) * 72 + nt * 16 + l15] = f2bf(prA[nt][r]);
        f32x4 oA = {};
        #pragma unroll
        for (int k2 = 0; k2 < 2; ++k2) {
            short8 ap  = *(const short8*)(ps + l15 * 72 + k2 * 32 + quad * 8);
            short8 bv8 = *(const short8*)(vtreg + hA * (16 * STR_VT) + l15 * STR_VT + k2 * 32 + quad * 8);
            oA = MFMA(ap, bv8, oA);
        }
        #pragma unroll
        for (int r = 0; r < 4; ++r) oA[r] *= invA4[r];
        // P-B write + PV-B (same addresses; same-wave LDS ordering)
        asm volatile("" ::: "memory");
        #pragma unroll
        for (int nt = 0; nt < 4; ++nt)
            #pragma unroll
            for (int r = 0; r < 4; ++r)
                ps[(quad * 4 + r) * 72 + nt * 16 + l15] = f2bf(prB[nt][r]);
        f32x4 oB = {};
        #pragma unroll
        for (int k2 = 0; k2 < 2; ++k2) {
            short8 ap  = *(const short8*)(ps + l15 * 72 + k2 * 32 + quad * 8);
            short8 bv8 = *(const short8*)(vtreg + hB * (16 * STR_VT) + l15 * STR_VT + k2 * 32 + quad * 8);
            oB = MFMA(ap, bv8, oB);
        }
        #pragma unroll
        for (int r = 0; r < 4; ++r) oB[r] *= invB4[r];
        accO[hA] = oA; accO[hB] = oB;
    }
    __syncthreads();   // B5: all K16' reads done before A-region reuse as obuf

    // ---- concat heads into obuf (own-wave rows) + out projection + store ----
    float bor_[6];
    #pragma unroll
    for (int h = 0; h < 6; ++h) bor_[h] = bo[h * 16 + l15];
    ushort* obuf = A;
    #pragma unroll
    for (int h = 0; h < 6; ++h)
        #pragma unroll
        for (int r = 0; r < 4; ++r)
            obuf[(mt * 16 + quad * 4 + r) * STR_A + h * 16 + l15] = f2bf(accO[h][r]);

    {
        int t0 = mt * 16 + quad * 4;
        int i = t0 >> 3, j0 = t0 & 7;
        short8 oa0 = *(const short8*)(obuf + arow);
        short8 oa1 = *(const short8*)(obuf + arow + 32);
        short8 oa2 = *(const short8*)(obuf + arow + 64);
        short8 wo0 = *(const short8*)(ws + WS_WOT + (0 * 64 + lane) * 8);
        short8 wo1 = *(const short8*)(ws + WS_WOT + (1 * 64 + lane) * 8);
        short8 wo2 = *(const short8*)(ws + WS_WOT + (2 * 64 + lane) * 8);
        #pragma unroll
        for (int nt = 0; nt < 6; ++nt) {
            short8 c0f = wo0, c1f = wo1, c2f = wo2;
            if (nt < 5) {
                wo0 = *(const short8*)(ws + WS_WOT + (((nt + 1) * 3 + 0) * 64 + lane) * 8);
                wo1 = *(const short8*)(ws + WS_WOT + (((nt + 1) * 3 + 1) * 64 + lane) * 8);
                wo2 = *(const short8*)(ws + WS_WOT + (((nt + 1) * 3 + 2) * 64 + lane) * 8);
            }
            f32x4 acc = {bor_[nt], bor_[nt], bor_[nt], bor_[nt]};
            acc = MFMA(oa0, c0f, acc);
            acc = MFMA(oa1, c1f, acc);
            acc = MFMA(oa2, c2f, acc);
            int cout = nt * 16 + l15;
            float4 v4 = make_float4(acc[0], acc[1], acc[2], acc[3]);
            float* dst = out + (size_t)(b * 96 + cout) * 65536 + (h0 + i) * 256 + w0 + j0;
            *(float4*)dst = v4;
        }
    }
}

extern "C" void kernel_launch(void* const* d_in, const int* in_sizes, int n_in,
                              void* d_out, int out_size, void* d_ws, size_t ws_size,
                              hipStream_t stream) {
    const float* xq   = (const float*)d_in[0];
    const float* xkv  = (const float*)d_in[1];
    const float* Wq   = (const float*)d_in[2];
    const float* bq   = (const float*)d_in[3];
    const float* Wk   = (const float*)d_in[4];
    const float* bk   = (const float*)d_in[5];
    const float* Wv   = (const float*)d_in[6];
    const float* bv   = (const float*)d_in[7];
    const float* btab = (const float*)d_in[8];
    const float* Wo   = (const float*)d_in[9];
    const float* bo   = (const float*)d_in[10];
    ushort* ws = (ushort*)d_ws;
    float* out = (float*)d_out;

    hipLaunchKernelGGL(prep_weights, dim3((WS_TOTAL + 255) / 256), dim3(256), 0, stream,
                       Wq, Wk, Wv, Wo, btab, ws);
    hipLaunchKernelGGL(swin_attn, dim3(4096), dim3(256), 0, stream,
                       xq, xkv, bq, bk, bv, bo, ws, out);
}